// Round 5
// baseline (819.767 us; speedup 1.0000x reference)
//
#include <hip/hip_runtime.h>

#define N_ATOMS 200000
#define N_BONDS 400000
#define MAX_NEI 10
#define N_MOLS  8000
#define AFD 87
#define BFD 6
#define H 64
#define WPB 16          // waves per block (1024 threads)
#define RPW 4           // rows per wave
#define RPB (WPB*RPW)   // 64 rows per block
#define NG  (RPW*MAX_NEI)   // 40 gathers per wave

// ---------------------------------------------------------------------------
// T: M1 = W_bemb @ V1 ; M2 = W_bemb @ W1   (both [6][64], one block)
// ---------------------------------------------------------------------------
__global__ __launch_bounds__(256) void k_tiny(
    const float* __restrict__ Wb, const float* __restrict__ V1,
    const float* __restrict__ W1, float* __restrict__ M1, float* __restrict__ M2)
{
    int t = threadIdx.x;
    for (int idx = t; idx < BFD * H; idx += 256) {
        int k = idx >> 6, h = idx & 63;
        float a1 = 0.f, a2 = 0.f;
        for (int j = 0; j < H; ++j) {
            float w = Wb[k * H + j];
            a1 = fmaf(w, V1[j * H + h], a1);
            a2 = fmaf(w, W1[j * H + h], a2);
        }
        M1[idx] = a1;
        M2[idx] = a2;
    }
}

// ---------------------------------------------------------------------------
// A: h_atom = af@Wemb ; g_atom0 = h_atom@V2.  4 rows/wave, transposed staging.
// ---------------------------------------------------------------------------
__global__ __launch_bounds__(1024, 8) void k_atom_emb(
    const float* __restrict__ af, const float* __restrict__ Wemb,
    const float* __restrict__ V2, float* __restrict__ h_atom,
    float* __restrict__ g_atom)
{
    __shared__ float sW[AFD * H];          // 22272 B
    __shared__ float sV[H * H];            // 16384 B
    __shared__ float sT[WPB * AFD * 4];    // 22272 B
    int tid = threadIdx.x;
    for (int t = tid; t < AFD * H / 4; t += 1024)
        ((float4*)sW)[t] = ((const float4*)Wemb)[t];
    ((float4*)sV)[tid] = ((const float4*)V2)[tid];
    int w = tid >> 6, h = tid & 63;
    int row0 = __builtin_amdgcn_readfirstlane((int)(blockIdx.x * RPB + w * RPW));
    float* myT = sT + w * (AFD * 4);
    for (int c = h; c < AFD; c += 64) {
#pragma unroll
        for (int i = 0; i < RPW; ++i)
            myT[c * 4 + i] = af[(size_t)(row0 + i) * AFD + c];
    }
    __syncthreads();
    const float4* myTv = (const float4*)myT;
    float a0 = 0.f, a1 = 0.f, a2 = 0.f, a3 = 0.f;
#pragma unroll 4
    for (int k = 0; k < AFD; ++k) {
        float u = sW[k * H + h];
        float4 s = myTv[k];
        a0 = fmaf(s.x, u, a0); a1 = fmaf(s.y, u, a1);
        a2 = fmaf(s.z, u, a2); a3 = fmaf(s.w, u, a3);
    }
    h_atom[(size_t)(row0 + 0) * H + h] = a0;
    h_atom[(size_t)(row0 + 1) * H + h] = a1;
    h_atom[(size_t)(row0 + 2) * H + h] = a2;
    h_atom[(size_t)(row0 + 3) * H + h] = a3;
    ((float4*)myT)[h] = make_float4(a0, a1, a2, a3);
    float g0 = 0.f, g1 = 0.f, g2 = 0.f, g3 = 0.f;
#pragma unroll 4
    for (int k = 0; k < H; ++k) {
        float v = sV[k * H + h];
        float4 s = myTv[k];
        g0 = fmaf(s.x, v, g0); g1 = fmaf(s.y, v, g1);
        g2 = fmaf(s.z, v, g2); g3 = fmaf(s.w, v, g3);
    }
    g_atom[(size_t)(row0 + 0) * H + h] = g0;
    g_atom[(size_t)(row0 + 1) * H + h] = g1;
    g_atom[(size_t)(row0 + 2) * H + h] = g2;
    g_atom[(size_t)(row0 + 3) * H + h] = g3;
}

// ---------------------------------------------------------------------------
// E: h_new = relu(h@U1 + nei@U2); extra = h_new@Mx.  4 rows/wave.
// MLP restructure: 40 uniform indices batch-loaded (s_load), 40 g_atom
// gathers issued up-front, U1 matmul overlaps gather latency.
// ---------------------------------------------------------------------------
__global__ __launch_bounds__(1024, 8) void k_update(
    const float* __restrict__ h_in, const float* __restrict__ g_atom,
    const float* __restrict__ bf, const float* __restrict__ M1,
    const int* __restrict__ ag, const int* __restrict__ bg,
    const float* __restrict__ U1, const float* __restrict__ U2,
    const float* __restrict__ Mx,
    float* __restrict__ h_out, float* __restrict__ extra_out)
{
    __shared__ float sU1[H * H];        // 16 KB
    __shared__ float sU2[H * H];        // 16 KB
    __shared__ float4 sRow[WPB][H];     // 16 KB
    __shared__ float4 sNei[WPB][H];     // 16 KB
    int tid = threadIdx.x;
    ((float4*)sU1)[tid] = ((const float4*)U1)[tid];
    ((float4*)sU2)[tid] = ((const float4*)U2)[tid];
    int w = tid >> 6, h = tid & 63;
    int row0 = __builtin_amdgcn_readfirstlane((int)(blockIdx.x * RPB + w * RPW));

    // --- uniform batched index loads (contiguous 40 ints -> s_load_dwordx8) ---
    const int* agp = ag + (size_t)row0 * MAX_NEI;
    int ia[NG];
#pragma unroll
    for (int k = 0; k < NG; ++k) ia[k] = agp[k];

    // --- issue all 40 g_atom gathers up-front (independent dests) ---
    float ga[NG];
#pragma unroll
    for (int k = 0; k < NG; ++k) ga[k] = g_atom[(size_t)ia[k] * H + h];

    // own-row loads + M1 column
    float m1c[BFD];
#pragma unroll
    for (int j = 0; j < BFD; ++j) m1c[j] = M1[j * H + h];
    float x0 = h_in[(size_t)(row0 + 0) * H + h];
    float x1 = h_in[(size_t)(row0 + 1) * H + h];
    float x2 = h_in[(size_t)(row0 + 2) * H + h];
    float x3 = h_in[(size_t)(row0 + 3) * H + h];

    __syncthreads();                      // sU1/sU2 ready
    sRow[w][h] = make_float4(x0, x1, x2, x3);

    // --- U1 matmul overlaps in-flight gathers ---
    float o0 = 0.f, o1 = 0.f, o2 = 0.f, o3 = 0.f;
#pragma unroll 4
    for (int k = 0; k < H; ++k) {
        float u = sU1[k * H + h];
        float4 s = sRow[w][k];
        o0 = fmaf(s.x, u, o0); o1 = fmaf(s.y, u, o1);
        o2 = fmaf(s.z, u, o2); o3 = fmaf(s.w, u, o3);
    }

    // --- bond-side uniform dots + relu-sum (consumes ga) ---
    const int* bgp = bg + (size_t)row0 * MAX_NEI;
    float nacc[RPW];
#pragma unroll
    for (int i = 0; i < RPW; ++i) {
        int ibr[MAX_NEI];
#pragma unroll
        for (int k = 0; k < MAX_NEI; ++k) ibr[k] = bgp[i * MAX_NEI + k];
        float a = 0.f;
#pragma unroll
        for (int k = 0; k < MAX_NEI; ++k) {
            const float* bp = bf + (size_t)ibr[k] * BFD;
            float gb = 0.f;
#pragma unroll
            for (int j = 0; j < BFD; ++j) gb = fmaf(bp[j], m1c[j], gb);
            a += fmaxf(gb + ga[i * MAX_NEI + k], 0.f);
        }
        nacc[i] = a;
    }
    sNei[w][h] = make_float4(nacc[0], nacc[1], nacc[2], nacc[3]);

    // --- U2 matmul ---
#pragma unroll 4
    for (int k = 0; k < H; ++k) {
        float u = sU2[k * H + h];
        float4 s = sNei[w][k];
        o0 = fmaf(s.x, u, o0); o1 = fmaf(s.y, u, o1);
        o2 = fmaf(s.z, u, o2); o3 = fmaf(s.w, u, o3);
    }
    o0 = fmaxf(o0, 0.f); o1 = fmaxf(o1, 0.f);
    o2 = fmaxf(o2, 0.f); o3 = fmaxf(o3, 0.f);
    h_out[(size_t)(row0 + 0) * H + h] = o0;
    h_out[(size_t)(row0 + 1) * H + h] = o1;
    h_out[(size_t)(row0 + 2) * H + h] = o2;
    h_out[(size_t)(row0 + 3) * H + h] = o3;
    sRow[w][h] = make_float4(o0, o1, o2, o3);   // own-wave reuse as h_new

    // --- Mx matmul (Mx through L1, 16 KB resident) ---
    float g0 = 0.f, g1 = 0.f, g2 = 0.f, g3 = 0.f;
#pragma unroll 4
    for (int k = 0; k < H; ++k) {
        float u = Mx[k * H + h];
        float4 s = sRow[w][k];
        g0 = fmaf(s.x, u, g0); g1 = fmaf(s.y, u, g1);
        g2 = fmaf(s.z, u, g2); g3 = fmaf(s.w, u, g3);
    }
    extra_out[(size_t)(row0 + 0) * H + h] = g0;
    extra_out[(size_t)(row0 + 1) * H + h] = g1;
    extra_out[(size_t)(row0 + 2) * H + h] = g2;
    extra_out[(size_t)(row0 + 3) * H + h] = g3;
}

// ---------------------------------------------------------------------------
// F: c_atom[i,h] = (h2@W0)[i,h] * sum_k p_atom[ag[i,k],h]*(bf[bg[i,k]]@M2)[h]
// ---------------------------------------------------------------------------
__global__ __launch_bounds__(1024, 8) void k_catom(
    const float* __restrict__ h2, const float* __restrict__ p_atom,
    const float* __restrict__ bf, const float* __restrict__ M2,
    const int* __restrict__ ag, const int* __restrict__ bg,
    const float* __restrict__ W0, float* __restrict__ c_atom)
{
    __shared__ float sW[H * H];         // 16 KB
    __shared__ float4 sRow[WPB][H];     // 16 KB
    int tid = threadIdx.x;
    ((float4*)sW)[tid] = ((const float4*)W0)[tid];
    int w = tid >> 6, h = tid & 63;
    int row0 = __builtin_amdgcn_readfirstlane((int)(blockIdx.x * RPB + w * RPW));

    const int* agp = ag + (size_t)row0 * MAX_NEI;
    int ia[NG];
#pragma unroll
    for (int k = 0; k < NG; ++k) ia[k] = agp[k];
    float pa[NG];
#pragma unroll
    for (int k = 0; k < NG; ++k) pa[k] = p_atom[(size_t)ia[k] * H + h];

    float m2c[BFD];
#pragma unroll
    for (int j = 0; j < BFD; ++j) m2c[j] = M2[j * H + h];
    float x0 = h2[(size_t)(row0 + 0) * H + h];
    float x1 = h2[(size_t)(row0 + 1) * H + h];
    float x2 = h2[(size_t)(row0 + 2) * H + h];
    float x3 = h2[(size_t)(row0 + 3) * H + h];
    __syncthreads();                    // sW ready
    sRow[w][h] = make_float4(x0, x1, x2, x3);

    // W0 matmul overlaps gathers
    float f0 = 0.f, f1 = 0.f, f2 = 0.f, f3 = 0.f;
#pragma unroll 4
    for (int k = 0; k < H; ++k) {
        float u = sW[k * H + h];
        float4 s = sRow[w][k];
        f0 = fmaf(s.x, u, f0); f1 = fmaf(s.y, u, f1);
        f2 = fmaf(s.z, u, f2); f3 = fmaf(s.w, u, f3);
    }

    const int* bgp = bg + (size_t)row0 * MAX_NEI;
    float sacc[RPW];
#pragma unroll
    for (int i = 0; i < RPW; ++i) {
        int ibr[MAX_NEI];
#pragma unroll
        for (int k = 0; k < MAX_NEI; ++k) ibr[k] = bgp[i * MAX_NEI + k];
        float a = 0.f;
#pragma unroll
        for (int k = 0; k < MAX_NEI; ++k) {
            const float* bp = bf + (size_t)ibr[k] * BFD;
            float pb = 0.f;
#pragma unroll
            for (int j = 0; j < BFD; ++j) pb = fmaf(bp[j], m2c[j], pb);
            a = fmaf(pa[i * MAX_NEI + k], pb, a);
        }
        sacc[i] = a;
    }
    c_atom[(size_t)(row0 + 0) * H + h] = f0 * sacc[0];
    c_atom[(size_t)(row0 + 1) * H + h] = f1 * sacc[1];
    c_atom[(size_t)(row0 + 2) * H + h] = f2 * sacc[2];
    c_atom[(size_t)(row0 + 3) * H + h] = f3 * sacc[3];
}

// ---------------------------------------------------------------------------
// H: c_mol[m] = sum over contiguous atom slice (mol_ids sorted, binary search)
// ---------------------------------------------------------------------------
__global__ void k_segsum(
    const float* __restrict__ c_atom, const int* __restrict__ mol_ids,
    float* __restrict__ c_mol)
{
    int m = blockIdx.x;
    int h = threadIdx.x;           // 64 threads
    int lo = 0, hi = N_ATOMS;
    while (lo < hi) { int mid = (lo + hi) >> 1; if (mol_ids[mid] < m) lo = mid + 1; else hi = mid; }
    int start = lo;
    hi = N_ATOMS;
    while (lo < hi) { int mid = (lo + hi) >> 1; if (mol_ids[mid] < m + 1) lo = mid + 1; else hi = mid; }
    int end = lo;
    float acc = 0.f;
    for (int a = start; a < end; ++a) acc += c_atom[a * H + h];
    c_mol[m * H + h] = acc;
}

extern "C" void kernel_launch(void* const* d_in, const int* in_sizes, int n_in,
                              void* d_out, int out_size, void* d_ws, size_t ws_size,
                              hipStream_t stream)
{
    const float* atom_feat = (const float*)d_in[0];
    const float* bond_feat = (const float*)d_in[1];
    const int*   ag        = (const int*)d_in[2];
    const int*   bg        = (const int*)d_in[3];
    const int*   mol_ids   = (const int*)d_in[4];
    const float* W_aemb    = (const float*)d_in[5];
    const float* W_bemb    = (const float*)d_in[6];
    const float* U1        = (const float*)d_in[7];
    const float* U2        = (const float*)d_in[8];
    const float* V         = (const float*)d_in[9];
    const float* W0        = (const float*)d_in[10];
    const float* W1        = (const float*)d_in[11];
    const float* W2        = (const float*)d_in[12];

    float* out    = (float*)d_out;
    float* c_mol  = out;
    float* c_atom = out + (size_t)N_MOLS * H;   // also g_atom pong scratch

    float* hA  = (float*)d_ws;                  // [N_ATOMS*H] h_atom (in-place)
    float* gA0 = hA  + (size_t)N_ATOMS * H;     // [N_ATOMS*H] g_atom ping
    float* M1  = gA0 + (size_t)N_ATOMS * H;     // [6*64]
    float* M2  = M1  + BFD * H;                 // [6*64]
    float* gA1 = c_atom;                        // pong in d_out (dead by k_catom)

    const float* V1 = V;            // V rows 0..63   (h_bond_nei part)
    const float* V2 = V + H * H;    // V rows 64..127 (h_atom_nei part)

    k_tiny<<<1, 256, 0, stream>>>(W_bemb, V1, W1, M1, M2);

    k_atom_emb<<<N_ATOMS / RPB, 1024, 0, stream>>>(atom_feat, W_aemb, V2, hA, gA0);

    // iter 0: h1 = relu(h0@U1 + nei@U2); gA1 = h1@V2
    k_update<<<N_ATOMS / RPB, 1024, 0, stream>>>(hA, gA0, bond_feat, M1, ag, bg,
                                                 U1, U2, V2, hA, gA1);
    // iter 1: h2 = relu(h1@U1 + nei@U2); gA0 = p_atom = h2@W2
    k_update<<<N_ATOMS / RPB, 1024, 0, stream>>>(hA, gA1, bond_feat, M1, ag, bg,
                                                 U1, U2, W2, hA, gA0);

    // iter 2 (last): c_atom = (h2@W0) * sum_k p_atom[ag]*(bf[bg]@M2)
    k_catom<<<N_ATOMS / RPB, 1024, 0, stream>>>(hA, gA0, bond_feat, M2, ag, bg,
                                                W0, c_atom);

    k_segsum<<<N_MOLS, 64, 0, stream>>>(c_atom, mol_ids, c_mol);
}

// Round 7
// 799.593 us; speedup vs baseline: 1.0252x; 1.0252x over previous
//
#include <hip/hip_runtime.h>

#define N_ATOMS 200000
#define N_BONDS 400000
#define MAX_NEI 10
#define N_MOLS  8000
#define AFD 87
#define BFD 6
#define H 64
#define WPB 16          // waves per block (1024 threads)
#define RPW 4           // rows per wave
#define RPB (WPB*RPW)   // 64 rows per block

#define NT_LD(p)     __builtin_nontemporal_load(p)
#define NT_ST(p, v)  __builtin_nontemporal_store((v), (p))

// ---------------------------------------------------------------------------
// T: M1 = W_bemb @ V1 ; M2 = W_bemb @ W1   (both [6][64], one block)
// ---------------------------------------------------------------------------
__global__ __launch_bounds__(256) void k_tiny(
    const float* __restrict__ Wb, const float* __restrict__ V1,
    const float* __restrict__ W1, float* __restrict__ M1, float* __restrict__ M2)
{
    int t = threadIdx.x;
    for (int idx = t; idx < BFD * H; idx += 256) {
        int k = idx >> 6, h = idx & 63;
        float a1 = 0.f, a2 = 0.f;
        for (int j = 0; j < H; ++j) {
            float w = Wb[k * H + j];
            a1 = fmaf(w, V1[j * H + h], a1);
            a2 = fmaf(w, W1[j * H + h], a2);
        }
        M1[idx] = a1;
        M2[idx] = a2;
    }
}

// ---------------------------------------------------------------------------
// A: h_atom = af@Wemb ; g_atom0 = h_atom@V2.  4 rows/wave, transposed staging.
// af load + h_atom store are non-temporal (single-use streams);
// g_atom store stays cached (it is iter-0's gather target -> pre-warms L3).
// ---------------------------------------------------------------------------
__global__ __launch_bounds__(1024, 8) void k_atom_emb(
    const float* __restrict__ af, const float* __restrict__ Wemb,
    const float* __restrict__ V2, float* __restrict__ h_atom,
    float* __restrict__ g_atom)
{
    __shared__ float sW[AFD * H];          // 22272 B
    __shared__ float sV[H * H];            // 16384 B
    __shared__ float sT[WPB * AFD * 4];    // 22272 B
    int tid = threadIdx.x;
    for (int t = tid; t < AFD * H / 4; t += 1024)
        ((float4*)sW)[t] = ((const float4*)Wemb)[t];
    ((float4*)sV)[tid] = ((const float4*)V2)[tid];
    int w = tid >> 6, h = tid & 63;
    int row0 = __builtin_amdgcn_readfirstlane((int)(blockIdx.x * RPB + w * RPW));
    float* myT = sT + w * (AFD * 4);
    for (int c = h; c < AFD; c += 64) {
#pragma unroll
        for (int i = 0; i < RPW; ++i)
            myT[c * 4 + i] = NT_LD(&af[(size_t)(row0 + i) * AFD + c]);
    }
    __syncthreads();
    const float4* myTv = (const float4*)myT;
    float a0 = 0.f, a1 = 0.f, a2 = 0.f, a3 = 0.f;
#pragma unroll 4
    for (int k = 0; k < AFD; ++k) {
        float u = sW[k * H + h];
        float4 s = myTv[k];
        a0 = fmaf(s.x, u, a0); a1 = fmaf(s.y, u, a1);
        a2 = fmaf(s.z, u, a2); a3 = fmaf(s.w, u, a3);
    }
    NT_ST(&h_atom[(size_t)(row0 + 0) * H + h], a0);
    NT_ST(&h_atom[(size_t)(row0 + 1) * H + h], a1);
    NT_ST(&h_atom[(size_t)(row0 + 2) * H + h], a2);
    NT_ST(&h_atom[(size_t)(row0 + 3) * H + h], a3);
    ((float4*)myT)[h] = make_float4(a0, a1, a2, a3);
    float g0 = 0.f, g1 = 0.f, g2 = 0.f, g3 = 0.f;
#pragma unroll 4
    for (int k = 0; k < H; ++k) {
        float v = sV[k * H + h];
        float4 s = myTv[k];
        g0 = fmaf(s.x, v, g0); g1 = fmaf(s.y, v, g1);
        g2 = fmaf(s.z, v, g2); g3 = fmaf(s.w, v, g3);
    }
    g_atom[(size_t)(row0 + 0) * H + h] = g0;
    g_atom[(size_t)(row0 + 1) * H + h] = g1;
    g_atom[(size_t)(row0 + 2) * H + h] = g2;
    g_atom[(size_t)(row0 + 3) * H + h] = g3;
}

// ---------------------------------------------------------------------------
// E: h_new = relu(h@U1 + nei@U2); extra = h_new@Mx.  4 rows/wave.
// nei[i,h] = sum_k relu( (bf[bg[i,k]]@M1)[h] + g_atom[ag[i,k],h] )
// Streams (h_in load, h_out store) are non-temporal; gather targets
// (g_atom, bf) and extra_out (next kernel's gather target) stay cached.
// ---------------------------------------------------------------------------
#define GATHER_NEI(i, OUT) do {                                              \
    const int* agp = ag + (size_t)(row0 + (i)) * MAX_NEI;                    \
    const int* bgp = bg + (size_t)(row0 + (i)) * MAX_NEI;                    \
    float a = 0.f;                                                           \
    _Pragma("unroll")                                                        \
    for (int k = 0; k < MAX_NEI; ++k) {                                      \
        int ia = agp[k];                                                     \
        int ib = bgp[k];                                                     \
        float ga = g_atom[(size_t)ia * H + h];                               \
        const float* bp = bf + (size_t)ib * BFD;                             \
        float gb = 0.f;                                                      \
        _Pragma("unroll")                                                    \
        for (int j = 0; j < BFD; ++j) gb = fmaf(bp[j], m1c[j], gb);          \
        a += fmaxf(gb + ga, 0.f);                                            \
    }                                                                        \
    OUT = a;                                                                 \
} while (0)

__global__ __launch_bounds__(1024, 8) void k_update(
    const float* __restrict__ h_in, const float* __restrict__ g_atom,
    const float* __restrict__ bf, const float* __restrict__ M1,
    const int* __restrict__ ag, const int* __restrict__ bg,
    const float* __restrict__ U1, const float* __restrict__ U2,
    const float* __restrict__ Mx,
    float* __restrict__ h_out, float* __restrict__ extra_out)
{
    __shared__ float sU1[H * H];        // 16 KB
    __shared__ float sU2[H * H];        // 16 KB
    __shared__ float4 sRow[WPB][H];     // 16 KB
    __shared__ float4 sNei[WPB][H];     // 16 KB
    int tid = threadIdx.x;
    ((float4*)sU1)[tid] = ((const float4*)U1)[tid];
    ((float4*)sU2)[tid] = ((const float4*)U2)[tid];
    int w = tid >> 6, h = tid & 63;
    int row0 = __builtin_amdgcn_readfirstlane((int)(blockIdx.x * RPB + w * RPW));
    float m1c[BFD];
#pragma unroll
    for (int j = 0; j < BFD; ++j) m1c[j] = M1[j * H + h];
    float x0 = NT_LD(&h_in[(size_t)(row0 + 0) * H + h]);
    float x1 = NT_LD(&h_in[(size_t)(row0 + 1) * H + h]);
    float x2 = NT_LD(&h_in[(size_t)(row0 + 2) * H + h]);
    float x3 = NT_LD(&h_in[(size_t)(row0 + 3) * H + h]);
    sRow[w][h] = make_float4(x0, x1, x2, x3);
    float n0, n1, n2, n3;
    GATHER_NEI(0, n0);
    GATHER_NEI(1, n1);
    GATHER_NEI(2, n2);
    GATHER_NEI(3, n3);
    sNei[w][h] = make_float4(n0, n1, n2, n3);
    __syncthreads();
    float o0 = 0.f, o1 = 0.f, o2 = 0.f, o3 = 0.f;
#pragma unroll 4
    for (int k = 0; k < H; ++k) {
        float u = sU1[k * H + h];
        float4 s = sRow[w][k];
        o0 = fmaf(s.x, u, o0); o1 = fmaf(s.y, u, o1);
        o2 = fmaf(s.z, u, o2); o3 = fmaf(s.w, u, o3);
    }
#pragma unroll 4
    for (int k = 0; k < H; ++k) {
        float u = sU2[k * H + h];
        float4 s = sNei[w][k];
        o0 = fmaf(s.x, u, o0); o1 = fmaf(s.y, u, o1);
        o2 = fmaf(s.z, u, o2); o3 = fmaf(s.w, u, o3);
    }
    o0 = fmaxf(o0, 0.f); o1 = fmaxf(o1, 0.f);
    o2 = fmaxf(o2, 0.f); o3 = fmaxf(o3, 0.f);
    NT_ST(&h_out[(size_t)(row0 + 0) * H + h], o0);
    NT_ST(&h_out[(size_t)(row0 + 1) * H + h], o1);
    NT_ST(&h_out[(size_t)(row0 + 2) * H + h], o2);
    NT_ST(&h_out[(size_t)(row0 + 3) * H + h], o3);
    sRow[w][h] = make_float4(o0, o1, o2, o3);          // reuse as snew (own wave)
    float g0 = 0.f, g1 = 0.f, g2 = 0.f, g3 = 0.f;
#pragma unroll 4
    for (int k = 0; k < H; ++k) {
        float u = Mx[k * H + h];                       // L1/L2-resident 16 KB
        float4 s = sRow[w][k];
        g0 = fmaf(s.x, u, g0); g1 = fmaf(s.y, u, g1);
        g2 = fmaf(s.z, u, g2); g3 = fmaf(s.w, u, g3);
    }
    extra_out[(size_t)(row0 + 0) * H + h] = g0;        // cached: next gather target
    extra_out[(size_t)(row0 + 1) * H + h] = g1;
    extra_out[(size_t)(row0 + 2) * H + h] = g2;
    extra_out[(size_t)(row0 + 3) * H + h] = g3;
}

// ---------------------------------------------------------------------------
// F: c_atom[i,h] = (h2@W0)[i,h] * sum_k p_atom[ag[i,k],h]*(bf[bg[i,k]]@M2)[h]
// h2 load non-temporal; p_atom/bf cached; c_atom store cached (read by segsum).
// ---------------------------------------------------------------------------
__global__ __launch_bounds__(1024, 8) void k_catom(
    const float* __restrict__ h2, const float* __restrict__ p_atom,
    const float* __restrict__ bf, const float* __restrict__ M2,
    const int* __restrict__ ag, const int* __restrict__ bg,
    const float* __restrict__ W0, float* __restrict__ c_atom)
{
    __shared__ float sW[H * H];         // 16 KB
    __shared__ float4 sRow[WPB][H];     // 16 KB
    int tid = threadIdx.x;
    ((float4*)sW)[tid] = ((const float4*)W0)[tid];
    int w = tid >> 6, h = tid & 63;
    int row0 = __builtin_amdgcn_readfirstlane((int)(blockIdx.x * RPB + w * RPW));
    float m2c[BFD];
#pragma unroll
    for (int j = 0; j < BFD; ++j) m2c[j] = M2[j * H + h];
    float x0 = NT_LD(&h2[(size_t)(row0 + 0) * H + h]);
    float x1 = NT_LD(&h2[(size_t)(row0 + 1) * H + h]);
    float x2 = NT_LD(&h2[(size_t)(row0 + 2) * H + h]);
    float x3 = NT_LD(&h2[(size_t)(row0 + 3) * H + h]);
    sRow[w][h] = make_float4(x0, x1, x2, x3);
    float s0, s1, s2, s3;
#define GATHER_PROD(i, OUT) do {                                             \
    const int* agp = ag + (size_t)(row0 + (i)) * MAX_NEI;                    \
    const int* bgp = bg + (size_t)(row0 + (i)) * MAX_NEI;                    \
    float a = 0.f;                                                           \
    _Pragma("unroll")                                                        \
    for (int k = 0; k < MAX_NEI; ++k) {                                      \
        int ia = agp[k];                                                     \
        int ib = bgp[k];                                                     \
        float pa = p_atom[(size_t)ia * H + h];                               \
        const float* bp = bf + (size_t)ib * BFD;                             \
        float pb = 0.f;                                                      \
        _Pragma("unroll")                                                    \
        for (int j = 0; j < BFD; ++j) pb = fmaf(bp[j], m2c[j], pb);          \
        a = fmaf(pa, pb, a);                                                 \
    }                                                                        \
    OUT = a;                                                                 \
} while (0)
    GATHER_PROD(0, s0);
    GATHER_PROD(1, s1);
    GATHER_PROD(2, s2);
    GATHER_PROD(3, s3);
    __syncthreads();
    float f0 = 0.f, f1 = 0.f, f2 = 0.f, f3 = 0.f;
#pragma unroll 4
    for (int k = 0; k < H; ++k) {
        float u = sW[k * H + h];
        float4 s = sRow[w][k];
        f0 = fmaf(s.x, u, f0); f1 = fmaf(s.y, u, f1);
        f2 = fmaf(s.z, u, f2); f3 = fmaf(s.w, u, f3);
    }
    c_atom[(size_t)(row0 + 0) * H + h] = f0 * s0;
    c_atom[(size_t)(row0 + 1) * H + h] = f1 * s1;
    c_atom[(size_t)(row0 + 2) * H + h] = f2 * s2;
    c_atom[(size_t)(row0 + 3) * H + h] = f3 * s3;
}

// ---------------------------------------------------------------------------
// H: c_mol[m] = sum over contiguous atom slice (mol_ids sorted, binary search)
// ---------------------------------------------------------------------------
__global__ void k_segsum(
    const float* __restrict__ c_atom, const int* __restrict__ mol_ids,
    float* __restrict__ c_mol)
{
    int m = blockIdx.x;
    int h = threadIdx.x;           // 64 threads
    int lo = 0, hi = N_ATOMS;
    while (lo < hi) { int mid = (lo + hi) >> 1; if (mol_ids[mid] < m) lo = mid + 1; else hi = mid; }
    int start = lo;
    hi = N_ATOMS;
    while (lo < hi) { int mid = (lo + hi) >> 1; if (mol_ids[mid] < m + 1) lo = mid + 1; else hi = mid; }
    int end = lo;
    float acc = 0.f;
    for (int a = start; a < end; ++a) acc += c_atom[a * H + h];
    c_mol[m * H + h] = acc;
}

extern "C" void kernel_launch(void* const* d_in, const int* in_sizes, int n_in,
                              void* d_out, int out_size, void* d_ws, size_t ws_size,
                              hipStream_t stream)
{
    const float* atom_feat = (const float*)d_in[0];
    const float* bond_feat = (const float*)d_in[1];
    const int*   ag        = (const int*)d_in[2];
    const int*   bg        = (const int*)d_in[3];
    const int*   mol_ids   = (const int*)d_in[4];
    const float* W_aemb    = (const float*)d_in[5];
    const float* W_bemb    = (const float*)d_in[6];
    const float* U1        = (const float*)d_in[7];
    const float* U2        = (const float*)d_in[8];
    const float* V         = (const float*)d_in[9];
    const float* W0        = (const float*)d_in[10];
    const float* W1        = (const float*)d_in[11];
    const float* W2        = (const float*)d_in[12];

    float* out    = (float*)d_out;
    float* c_mol  = out;
    float* c_atom = out + (size_t)N_MOLS * H;   // also g_atom pong scratch

    float* hA  = (float*)d_ws;                  // [N_ATOMS*H] h_atom (in-place)
    float* gA0 = hA  + (size_t)N_ATOMS * H;     // [N_ATOMS*H] g_atom ping
    float* M1  = gA0 + (size_t)N_ATOMS * H;     // [6*64]
    float* M2  = M1  + BFD * H;                 // [6*64]
    float* gA1 = c_atom;                        // pong in d_out (dead by k_catom)

    const float* V1 = V;            // V rows 0..63   (h_bond_nei part)
    const float* V2 = V + H * H;    // V rows 64..127 (h_atom_nei part)

    k_tiny<<<1, 256, 0, stream>>>(W_bemb, V1, W1, M1, M2);

    k_atom_emb<<<N_ATOMS / RPB, 1024, 0, stream>>>(atom_feat, W_aemb, V2, hA, gA0);

    // iter 0: h1 = relu(h0@U1 + nei@U2); gA1 = h1@V2
    k_update<<<N_ATOMS / RPB, 1024, 0, stream>>>(hA, gA0, bond_feat, M1, ag, bg,
                                                 U1, U2, V2, hA, gA1);
    // iter 1: h2 = relu(h1@U1 + nei@U2); gA0 = p_atom = h2@W2
    k_update<<<N_ATOMS / RPB, 1024, 0, stream>>>(hA, gA1, bond_feat, M1, ag, bg,
                                                 U1, U2, W2, hA, gA0);

    // iter 2 (last): c_atom = (h2@W0) * sum_k p_atom[ag]*(bf[bg]@M2)
    k_catom<<<N_ATOMS / RPB, 1024, 0, stream>>>(hA, gA0, bond_feat, M2, ag, bg,
                                                W0, c_atom);

    k_segsum<<<N_MOLS, 64, 0, stream>>>(c_atom, mol_ids, c_mol);
}